// Round 6
// baseline (21.431 us; speedup 1.0000x reference)
//
#include <hip/hip_runtime.h>

// 3x3 median filter, reflect padding, fp32, NCHW (4,3,1024,1024).
// 256 threads = full 1024-wide row (4 px/thread as float4); each block
// computes R=8 rows (1536 blocks -> 24 waves/CU). TRUE software pipeline:
//   iter r: ISSUE load of row r+2 (raw regs, no consumption)
//           FINALIZE row r+1 (shuffles/halos; its load was issued at r-1,
//                             so a full iteration separates issue from wait)
//           COMPUTE median of rows r-1..r+1, nt-store row r.
// Previous version shuffled at issue time, forcing vmcnt(0) immediately
// after each load -> exposed latency every iteration. This fixes that.
// XCD-chunked swizzle; median = med3(max3(lo), med3(mi), min3(hi)).

constexpr int R = 8;
constexpr int NXCD = 8;

typedef float f32x4 __attribute__((ext_vector_type(4)));

__device__ __forceinline__ float med3(float a, float b, float c) {
  return __builtin_amdgcn_fmed3f(a, b, c);
}

struct Raw { float4 m; float lh, rh; };

__global__ __launch_bounds__(256) void median3x3_kernel(
    const float* __restrict__ in, float* __restrict__ out, int H, int W,
    int tiles_per_plane, int chunk) {
  const int wg  = blockIdx.x;
  const int swz = (wg & (NXCD - 1)) * chunk + (wg >> 3);
  const int plane = swz / tiles_per_plane;
  const int y0    = (swz % tiles_per_plane) * R;

  const int tid  = threadIdx.x;
  const int x0   = tid * 4;
  const int lane = tid & 63;
  const bool ledge = (x0 == 0);          // reflect col -1 -> 1  (= m.y)
  const bool redge = (x0 + 4 >= W);      // reflect col W  -> W-2 (= m.z)

  const float* p = in  + (size_t)plane * H * W;
  float*       q = out + (size_t)plane * H * W;

  // ISSUE: start loads for row y; no use of the results here.
  auto issue = [&](int y, Raw& rw) {
    const float* rp = p + (size_t)y * W;
    rw.m = *reinterpret_cast<const float4*>(rp + x0);
    if (lane == 0 && !ledge)  rw.lh = rp[x0 - 1];   // cross-wave halo
    if (lane == 63 && !redge) rw.rh = rp[x0 + 4];
  };

  // FINALIZE: shuffles + halo select (this is where the vmcnt wait lands).
  auto finalize = [&](const Raw& rw, float (&v)[6]) {
    float lh = __shfl_up(rw.m.w, 1);
    float rh = __shfl_down(rw.m.x, 1);
    if (lane == 0)  lh = ledge ? rw.m.y : rw.lh;
    if (lane == 63) rh = redge ? rw.m.z : rw.rh;
    v[0] = lh; v[1] = rw.m.x; v[2] = rw.m.y; v[3] = rw.m.z; v[4] = rw.m.w; v[5] = rh;
  };

  float v[3][6];
  Raw raw[2], r0, r1;

  // prime: rows ym (reflect -1 -> 1), y0, y0+1
  issue(y0 == 0 ? 1 : y0 - 1, r0);
  issue(y0, r1);
  issue(y0 + 1, raw[1]);            // consumed at iter 0's finalize
  finalize(r0, v[0]);
  finalize(r1, v[1]);

  #pragma unroll
  for (int r = 0; r < R; ++r) {
    if (r < R - 1) {                // issue row r+2 (consumed at iter r+1)
      int y2 = y0 + r + 2;
      y2 = (y2 >= H) ? 2 * H - 2 - y2 : y2;   // reflect: H -> H-2
      issue(y2, raw[r & 1]);
    }
    finalize(raw[(r + 1) & 1], v[(r + 2) % 3]);  // row r+1, issued at r-1

    const float (&a)[6] = v[r % 3];
    const float (&b)[6] = v[(r + 1) % 3];
    const float (&c)[6] = v[(r + 2) % 3];

    // per-column sorted vertical triple (non-destructive)
    float lo[6], mi[6], hi[6];
    #pragma unroll
    for (int j = 0; j < 6; ++j) {
      const float plo = fminf(b[j], c[j]);
      const float phi = fmaxf(b[j], c[j]);
      lo[j] = fminf(a[j], plo);
      hi[j] = fmaxf(a[j], phi);
      mi[j] = fmaxf(plo, fminf(a[j], phi));
    }

    f32x4 o;
    #pragma unroll
    for (int i = 0; i < 4; ++i) {
      const float mxlo = fmaxf(fmaxf(lo[i], lo[i + 1]), lo[i + 2]);
      const float mnhi = fminf(fminf(hi[i], hi[i + 1]), hi[i + 2]);
      const float mdmi = med3(mi[i], mi[i + 1], mi[i + 2]);
      o[i] = med3(mxlo, mdmi, mnhi);
    }
    __builtin_nontemporal_store(o,
        reinterpret_cast<f32x4*>(q + (size_t)(y0 + r) * W + x0));
  }
}

extern "C" void kernel_launch(void* const* d_in, const int* in_sizes, int n_in,
                              void* d_out, int out_size, void* d_ws, size_t ws_size,
                              hipStream_t stream) {
  const float* x = (const float*)d_in[0];
  float* out = (float*)d_out;

  const int H = 1024, W = 1024;
  const int planes = in_sizes[0] / (H * W);      // B*C = 12
  const int tiles_per_plane = H / R;             // 128
  const int nblocks = planes * tiles_per_plane;  // 1536 (divisible by 8)
  const int chunk = nblocks / NXCD;              // 192

  dim3 grid(nblocks);
  dim3 block(W / 4);  // 256 threads, 4 px each
  median3x3_kernel<<<grid, block, 0, stream>>>(x, out, H, W,
                                               tiles_per_plane, chunk);
}

// Round 7
// 21.175 us; speedup vs baseline: 1.0121x; 1.0121x over previous
//
#include <hip/hip_runtime.h>

// 3x3 median filter, reflect padding, fp32, NCHW (4,3,1024,1024).
// 256 threads = full 1024-wide row (4 px/thread as float4); each block
// computes R=8 rows (1536 blocks -> 24 waves/CU), software-pipelined:
//   iter r: ISSUE load of row r+2, FINALIZE row r+1 (shuffles/halos),
//           COMPUTE median of rows r-1..r+1, store row r.
// XCD-chunked swizzle keeps vertically-adjacent blocks on the same XCD L2.
// A/B this round: plain stores instead of nontemporal (nt may bypass L2
// write buffering and cap the write stream below the 6.7 TB/s fills hit).
// Median-of-9 = column decomposition: med3(max3(lo), med3(mi), min3(hi)).

constexpr int R = 8;
constexpr int NXCD = 8;

__device__ __forceinline__ float med3(float a, float b, float c) {
  return __builtin_amdgcn_fmed3f(a, b, c);
}

struct Raw { float4 m; float lh, rh; };

__global__ __launch_bounds__(256) void median3x3_kernel(
    const float* __restrict__ in, float* __restrict__ out, int H, int W,
    int tiles_per_plane, int chunk) {
  const int wg  = blockIdx.x;
  const int swz = (wg & (NXCD - 1)) * chunk + (wg >> 3);
  const int plane = swz / tiles_per_plane;
  const int y0    = (swz % tiles_per_plane) * R;

  const int tid  = threadIdx.x;
  const int x0   = tid * 4;
  const int lane = tid & 63;
  const bool ledge = (x0 == 0);          // reflect col -1 -> 1  (= m.y)
  const bool redge = (x0 + 4 >= W);      // reflect col W  -> W-2 (= m.z)

  const float* p = in  + (size_t)plane * H * W;
  float*       q = out + (size_t)plane * H * W;

  // ISSUE: start loads for row y; no use of the results here.
  auto issue = [&](int y, Raw& rw) {
    const float* rp = p + (size_t)y * W;
    rw.m = *reinterpret_cast<const float4*>(rp + x0);
    if (lane == 0 && !ledge)  rw.lh = rp[x0 - 1];   // cross-wave halo
    if (lane == 63 && !redge) rw.rh = rp[x0 + 4];
  };

  // FINALIZE: shuffles + halo select (vmcnt wait lands here).
  auto finalize = [&](const Raw& rw, float (&v)[6]) {
    float lh = __shfl_up(rw.m.w, 1);
    float rh = __shfl_down(rw.m.x, 1);
    if (lane == 0)  lh = ledge ? rw.m.y : rw.lh;
    if (lane == 63) rh = redge ? rw.m.z : rw.rh;
    v[0] = lh; v[1] = rw.m.x; v[2] = rw.m.y; v[3] = rw.m.z; v[4] = rw.m.w; v[5] = rh;
  };

  float v[3][6];
  Raw raw[2], r0, r1;

  // prime: rows ym (reflect -1 -> 1), y0, y0+1
  issue(y0 == 0 ? 1 : y0 - 1, r0);
  issue(y0, r1);
  issue(y0 + 1, raw[1]);            // consumed at iter 0's finalize
  finalize(r0, v[0]);
  finalize(r1, v[1]);

  #pragma unroll
  for (int r = 0; r < R; ++r) {
    if (r < R - 1) {                // issue row r+2 (consumed at iter r+1)
      int y2 = y0 + r + 2;
      y2 = (y2 >= H) ? 2 * H - 2 - y2 : y2;   // reflect: H -> H-2
      issue(y2, raw[r & 1]);
    }
    finalize(raw[(r + 1) & 1], v[(r + 2) % 3]);  // row r+1, issued at r-1

    const float (&a)[6] = v[r % 3];
    const float (&b)[6] = v[(r + 1) % 3];
    const float (&c)[6] = v[(r + 2) % 3];

    // per-column sorted vertical triple (non-destructive)
    float lo[6], mi[6], hi[6];
    #pragma unroll
    for (int j = 0; j < 6; ++j) {
      const float plo = fminf(b[j], c[j]);
      const float phi = fmaxf(b[j], c[j]);
      lo[j] = fminf(a[j], plo);
      hi[j] = fmaxf(a[j], phi);
      mi[j] = fmaxf(plo, fminf(a[j], phi));
    }

    float4 o;
    float* op = &o.x;
    #pragma unroll
    for (int i = 0; i < 4; ++i) {
      const float mxlo = fmaxf(fmaxf(lo[i], lo[i + 1]), lo[i + 2]);
      const float mnhi = fminf(fminf(hi[i], hi[i + 1]), hi[i + 2]);
      const float mdmi = med3(mi[i], mi[i + 1], mi[i + 2]);
      op[i] = med3(mxlo, mdmi, mnhi);
    }
    *reinterpret_cast<float4*>(q + (size_t)(y0 + r) * W + x0) = o;
  }
}

extern "C" void kernel_launch(void* const* d_in, const int* in_sizes, int n_in,
                              void* d_out, int out_size, void* d_ws, size_t ws_size,
                              hipStream_t stream) {
  const float* x = (const float*)d_in[0];
  float* out = (float*)d_out;

  const int H = 1024, W = 1024;
  const int planes = in_sizes[0] / (H * W);      // B*C = 12
  const int tiles_per_plane = H / R;             // 128
  const int nblocks = planes * tiles_per_plane;  // 1536 (divisible by 8)
  const int chunk = nblocks / NXCD;              // 192

  dim3 grid(nblocks);
  dim3 block(W / 4);  // 256 threads, 4 px each
  median3x3_kernel<<<grid, block, 0, stream>>>(x, out, H, W,
                                               tiles_per_plane, chunk);
}